// Round 2
// baseline (56.853 us; speedup 1.0000x reference)
//
#include <hip/hip_runtime.h>
#include <hip/hip_bf16.h>

// Reference: xs = arange(30, 400) -> N = 370 fp32 outputs.
//   idx_i = argmin_j (t_j - xs_i)  (SIGNED diff, first index wins ties)
//   f_i   = t_idx;  d = (xs - f)^2
//   yv    = d > 10 ? 0 : (10 - d)^2
//   out   = yv / max(yv)
//
// Latency-bound (1.5 KB total traffic). Single dispatch, SINGLE WAVE:
// 64 threads x 6 elements, no LDS, no __syncthreads, wave-shuffle max.

#define N_OUT 370
#define NPER 6  // 64 * 6 = 384 >= 370

__global__ __launch_bounds__(64) void freq_codebook_kernel(
    const float* __restrict__ x, const float* __restrict__ y,
    float* __restrict__ out) {
  const int i = threadIdx.x;

  const float t0 = x[0];
  const float t1 = y[0];

  float yv[NPER];
  float vmax = 0.0f;  // yv >= 0 always, so 0 is the identity (matches ref pad)

  #pragma unroll
  for (int j = 0; j < NPER; ++j) {
    const int e = i + j * 64;
    const float xs = 30.0f + (float)e;
    // argmin over signed diffs [t0 - xs, t1 - xs]; first index wins ties
    const float d0 = t0 - xs;
    const float d1 = t1 - xs;
    const float f = (d1 < d0) ? t1 : t0;
    float d = xs - f;
    d = d * d;
    const float w = 10.0f - d;
    float v = (d > 10.0f) ? 0.0f : w * w;
    if (e >= N_OUT) v = 0.0f;  // pad lanes contribute identity to max
    yv[j] = v;
    vmax = fmaxf(vmax, v);
  }

  // 64-lane butterfly max (single wave -> block-wide, no barrier needed)
  #pragma unroll
  for (int o = 32; o > 0; o >>= 1) vmax = fmaxf(vmax, __shfl_xor(vmax, o, 64));

  // exact division (not rcp-mul) to keep bit-exactness with the reference
  #pragma unroll
  for (int j = 0; j < NPER; ++j) {
    const int e = i + j * 64;
    if (e < N_OUT) out[e] = yv[j] / vmax;
  }
}

extern "C" void kernel_launch(void* const* d_in, const int* in_sizes, int n_in,
                              void* d_out, int out_size, void* d_ws,
                              size_t ws_size, hipStream_t stream) {
  const float* x = (const float*)d_in[0];
  const float* y = (const float*)d_in[1];
  float* out = (float*)d_out;
  freq_codebook_kernel<<<dim3(1), dim3(64), 0, stream>>>(x, y, out);
}